// Round 5
// baseline (751.519 us; speedup 1.0000x reference)
//
#include <hip/hip_runtime.h>
#include <cstdint>
#include <cstddef>

#define E_ 32
#define TOPK_ 4
#define H_ 1024
#define I_ 1024
#define T_ 2048
#define ALPHA_ 1.702f
#define LIMIT_ 7.0f
#define TP_ 66    // transpose LDS pad (elems)
#define NCH_ 32   // K chunks (K=1024 / BK=32)

// prep grid sections
#define NB_RTR_  2048
#define NB_CAST_ 1024
#define NB_TGUP_ 16384
#define NB_TDWN_ 8192

typedef __attribute__((ext_vector_type(8))) short s8;
typedef __attribute__((ext_vector_type(4))) float f4;

__device__ __forceinline__ unsigned short f2bf(float f) {
  unsigned int u = __float_as_uint(f);
  return (unsigned short)((u + 0x7fffu + ((u >> 16) & 1u)) >> 16);
}

// async global -> LDS, 16 B per lane. LDS dest wave-uniform base; HW writes
// base + lane*16. Global src per-lane (enables source-side swizzle).
__device__ __forceinline__ void gload_lds16(const unsigned short* g,
                                            unsigned short* l) {
  __builtin_amdgcn_global_load_lds(
      (const __attribute__((address_space(1))) void*)g,
      (__attribute__((address_space(3))) void*)l, 16, 0, 0);
}

// ---------------------------------------------------------------------------
// transpose+cast body (verified r1-r4): 64x64 tile, coalesced fp32 reads,
// coalesced b128 bf16 writes. deint=1 deinterleaves gate/up columns.
// ---------------------------------------------------------------------------
__device__ __forceinline__ void transpose_body(
    const float* __restrict__ src, unsigned short* __restrict__ dst,
    int src_rows, int src_cols, int deint, int e, int c0, int r0, int tid,
    unsigned short (*ldsT)[TP_]) {
  const float* sp = src + (size_t)e * src_rows * src_cols
                        + (size_t)r0 * src_cols + c0;
  int r = tid >> 2, cq = tid & 3;
  const float* rowp = sp + (size_t)r * src_cols + cq * 4;
  #pragma unroll
  for (int j = 0; j < 4; ++j) {
    float4 v = *(const float4*)(rowp + j * 16);
    int c = cq * 4 + j * 16;
    ldsT[c + 0][r] = f2bf(v.x);
    ldsT[c + 1][r] = f2bf(v.y);
    ldsT[c + 2][r] = f2bf(v.z);
    ldsT[c + 3][r] = f2bf(v.w);
  }
  __syncthreads();
  int co = tid >> 2, hq = tid & 3;
  s8 v0 = *(s8*)&ldsT[co][hq * 16];
  s8 v1 = *(s8*)&ldsT[co][hq * 16 + 8];
  int C = c0 + co;
  size_t out_off;
  if (deint) {
    out_off = (size_t)e * src_cols * src_rows
            + (size_t)(C & 1) * (src_cols >> 1) * src_rows
            + (size_t)(C >> 1) * src_rows + r0 + hq * 16;
  } else {
    out_off = (size_t)e * src_cols * src_rows
            + (size_t)C * src_rows + r0 + hq * 16;
  }
  *(s8*)(dst + out_off) = v0;
  *(s8*)(dst + out_off + 8) = v1;
}

// ---------------------------------------------------------------------------
// Kernel 1: fused prep = router | cast_x | transpose(gup) | transpose(dwn).
// One launch instead of four; sections are independent.
// ---------------------------------------------------------------------------
__global__ __launch_bounds__(256)
void prep_kernel(const float* __restrict__ x,
                 const float* __restrict__ rw,
                 const float* __restrict__ rb,
                 const float* __restrict__ gup,
                 const float* __restrict__ dwn,
                 float* __restrict__ scores,
                 int* __restrict__ counts,
                 int* __restrict__ tok_list,
                 float* __restrict__ w_list,
                 unsigned short* __restrict__ xbf,
                 unsigned short* __restrict__ wgu_b,
                 unsigned short* __restrict__ wdt_b) {
  __shared__ __align__(16) char smem[64 * TP_ * 2];
  int bid = blockIdx.x;
  int tid = threadIdx.x;

  if (bid < NB_RTR_) {
    // ---- router: one token per block, 256 threads ----
    float* partial = (float*)smem;            // 256
    float* logits  = partial + 256;           // 32
    int t = bid;
    int e = tid & 31, q = tid >> 5;           // q: 0..7, 128 elems each
    const float4* xp = (const float4*)(x + (size_t)t * H_ + q * 128);
    const float4* wp = (const float4*)(rw + (size_t)e * H_ + q * 128);
    float s = 0.f;
    #pragma unroll 8
    for (int h = 0; h < 32; ++h) {
      float4 a = xp[h], b = wp[h];
      s += a.x * b.x + a.y * b.y + a.z * b.z + a.w * b.w;
    }
    partial[tid] = s;
    __syncthreads();
    if (tid < 32) {
      float acc = 0.f;
      #pragma unroll
      for (int j = 0; j < 8; ++j) acc += partial[j * 32 + tid];
      logits[tid] = acc + rb[tid];
    }
    __syncthreads();
    if (tid == 0) {
      float l[E_];
      #pragma unroll
      for (int i = 0; i < E_; ++i) l[i] = logits[i];
      int idx[TOPK_]; float v[TOPK_];
      for (int k = 0; k < TOPK_; ++k) {
        int bi = 0; float bv = -1e30f;
        #pragma unroll
        for (int i = 0; i < E_; ++i)
          if (l[i] > bv) { bv = l[i]; bi = i; }
        idx[k] = bi; v[k] = bv; l[bi] = -1e30f;
      }
      float m = v[0], den = 0.f, w[TOPK_];
      #pragma unroll
      for (int k = 0; k < TOPK_; ++k) { w[k] = expf(v[k] - m); den += w[k]; }
      float inv = 1.f / den;
      float* srow = scores + (size_t)t * E_;
      #pragma unroll
      for (int i = 0; i < E_; ++i) srow[i] = 0.f;
      for (int k = 0; k < TOPK_; ++k) {
        float wk = w[k] * inv;
        srow[idx[k]] = wk;
        int pos = atomicAdd(&counts[idx[k]], 1);
        tok_list[idx[k] * T_ + pos] = t * TOPK_ + k;
        w_list[idx[k] * T_ + pos] = wk;
      }
    }
  } else if (bid < NB_RTR_ + NB_CAST_) {
    // ---- x fp32 -> bf16 ----
    int b2 = bid - NB_RTR_;
    size_t i = (size_t)(b2 * 256 + tid) * 8;
    float4 a = *(const float4*)(x + i);
    float4 b = *(const float4*)(x + i + 4);
    s8 v;
    v[0] = (short)f2bf(a.x); v[1] = (short)f2bf(a.y);
    v[2] = (short)f2bf(a.z); v[3] = (short)f2bf(a.w);
    v[4] = (short)f2bf(b.x); v[5] = (short)f2bf(b.y);
    v[6] = (short)f2bf(b.z); v[7] = (short)f2bf(b.w);
    *(s8*)(xbf + i) = v;
  } else if (bid < NB_RTR_ + NB_CAST_ + NB_TGUP_) {
    // ---- gate_up transpose+deinterleave: [E][H][2I] -> [E][2][I][H] bf16 ----
    int b3 = bid - (NB_RTR_ + NB_CAST_);
    int e = b3 >> 9;          // 512 tiles per expert = 32 ctiles x 16 rtiles
    int rem = b3 & 511;
    int c0 = (rem & 31) * 64;
    int r0 = (rem >> 5) * 64;
    transpose_body(gup, wgu_b, H_, 2 * I_, 1, e, c0, r0, tid,
                   (unsigned short (*)[TP_])smem);
  } else {
    // ---- down transpose: [E][I][H] -> [E][H][I] bf16 ----
    int b4 = bid - (NB_RTR_ + NB_CAST_ + NB_TGUP_);
    int e = b4 >> 8;          // 256 tiles per expert = 16 x 16
    int rem = b4 & 255;
    int c0 = (rem & 15) * 64;
    int r0 = (rem >> 4) * 64;
    transpose_body(dwn, wdt_b, I_, H_, 0, e, c0, r0, tid,
                   (unsigned short (*)[TP_])smem);
  }
}

// ---------------------------------------------------------------------------
// Kernel 2: gate_up, bf16 MFMA, async gload_lds pipeline.
// Tile M=128 tokens x 64 i-cols (128 B-rows: 64 gate + 64 up), 4 waves in
// 2x2, wave-tile 64 tokens x 32 i (16 MFMA/chunk/wave). Source-side 16B-chunk
// XOR swizzle (chunk ^ ((row>>1)&3)) makes every ds_read_b128 2-way (free).
// Counted vmcnt(4): chunk c+2 loads stay in flight across barriers.
// XCD-clustered 1-D grid: 4 sibling token-blocks of one (e,itile) share B.
// ---------------------------------------------------------------------------
__global__ __launch_bounds__(256)
void gateup_mfma(const unsigned short* __restrict__ xb,   // [T][H] bf16
                 const unsigned short* __restrict__ wgu,  // [E][2][I][H] bf16
                 const float* __restrict__ gb,            // [E][2I]
                 const int* __restrict__ counts,
                 const int* __restrict__ tok_list,
                 unsigned short* __restrict__ act) {      // [T*4][I] bf16
  // 2048 blocks: xcd=lid&7; s=lid>>3 (0..255); e=xcd*4+(s>>6);
  // rem=s&63: itile=rem>>2 (0..15), tb=rem&3.
  int lid = blockIdx.x;
  int xcd = lid & 7, s = lid >> 3;
  int e = (xcd << 2) + (s >> 6);
  int rem = s & 63;
  int itile = rem >> 2;
  int tb = rem & 3;

  int cnt = counts[e];
  int t0 = tb * 128;
  if (t0 >= cnt) return;
  int tid = threadIdx.x;
  int lane = tid & 63;
  int wave = tid >> 6;
  int wm = wave >> 1, wn = wave & 1;

  __shared__ __align__(16) unsigned short Xs[2][128][32];
  __shared__ __align__(16) unsigned short Wg[2][128][32];
  __shared__ int toks[128];

  if (tid < 128) {
    int slot = t0 + tid;
    toks[tid] = (slot < cnt) ? tok_list[e * T_ + slot] : -1;
  }
  __syncthreads();

  int fm = lane & 15;
  int kc = lane >> 4;          // 0..3 (8-short chunk index)
  f4 accg[4][2] = {};
  f4 accu[4][2] = {};

  // ---- staging sources (per-lane, chunk-XOR-swizzled) ----
  // instr j of this wave covers LDS rows wave*32 + j*16 + (lane>>2),
  // phys chunk (lane&3); source global chunk = (lane&3) ^ ((row>>1)&3).
  int srow0 = (wave << 5) + (lane >> 2);
  int srow1 = srow0 + 16;
  int sc0 = ((lane & 3) ^ ((srow0 >> 1) & 3)) << 3;
  int sc1 = ((lane & 3) ^ ((srow1 >> 1) & 3)) << 3;
  int enc0 = toks[srow0], enc1 = toks[srow1];
  const unsigned short* srcA0 =
      xb + (size_t)((enc0 < 0) ? 0 : (enc0 >> 2)) * H_ + sc0;
  const unsigned short* srcA1 =
      xb + (size_t)((enc1 < 0) ? 0 : (enc1 >> 2)) * H_ + sc1;
  size_t R0 = (srow0 < 64) ? (size_t)(itile * 64 + srow0)
                           : (size_t)(I_ + itile * 64 + (srow0 - 64));
  size_t R1 = (srow1 < 64) ? (size_t)(itile * 64 + srow1)
                           : (size_t)(I_ + itile * 64 + (srow1 - 64));
  const unsigned short* wbase = wgu + (size_t)e * 2 * I_ * H_;
  const unsigned short* srcB0 = wbase + R0 * H_ + sc0;
  const unsigned short* srcB1 = wbase + R1 * H_ + sc1;

  // ---- read offsets (swizzled) ----
  int ar[4], ac[4];
  #pragma unroll
  for (int f = 0; f < 4; ++f) {
    int r = wm * 64 + f * 16 + fm;
    ar[f] = r;
    ac[f] = (kc ^ ((r >> 1) & 3)) << 3;
  }
  int brg[2], bcg[2];
  #pragma unroll
  for (int g = 0; g < 2; ++g) {
    int r = wn * 32 + g * 16 + fm;
    brg[g] = r;
    bcg[g] = (kc ^ ((r >> 1) & 3)) << 3;   // same xor for row r and r+64
  }

#define GU_ISSUE(CC, P)                                                      \
  {                                                                          \
    gload_lds16(srcA0 + (size_t)(CC) * 32, &Xs[P][(wave << 5)][0]);          \
    gload_lds16(srcA1 + (size_t)(CC) * 32, &Xs[P][(wave << 5) + 16][0]);     \
    gload_lds16(srcB0 + (size_t)(CC) * 32, &Wg[P][(wave << 5)][0]);          \
    gload_lds16(srcB1 + (size_t)(CC) * 32, &Wg[P][(wave << 5) + 16][0]);     \
  }

  GU_ISSUE(0, 0)
  GU_ISSUE(1, 1)
  asm volatile("s_waitcnt vmcnt(4)" ::: "memory");
  __builtin_amdgcn_s_barrier();
  asm volatile("" ::: "memory");

  for (int c = 0; c < NCH_; ++c) {
    int P = c & 1;
    {
      s8 a[4];
      #pragma unroll
      for (int f = 0; f < 4; ++f) a[f] = *(const s8*)&Xs[P][ar[f]][ac[f]];
      #pragma unroll
      for (int g = 0; g < 2; ++g) {
        s8 bg = *(const s8*)&Wg[P][brg[g]][bcg[g]];
        s8 bu = *(const s8*)&Wg[P][64 + brg[g]][bcg[g]];
        #pragma unroll
        for (int f = 0; f < 4; ++f) {
          accg[f][g] = __builtin_amdgcn_mfma_f32_16x16x32_bf16(a[f], bg, accg[f][g], 0, 0, 0);
          accu[f][g] = __builtin_amdgcn_mfma_f32_16x16x32_bf16(a[f], bu, accu[f][g], 0, 0, 0);
        }
      }
    }
    __builtin_amdgcn_s_barrier();          // all waves done reading buf P
    asm volatile("" ::: "memory");
    if (c < NCH_ - 2) {
      GU_ISSUE(c + 2, P)
      asm volatile("s_waitcnt vmcnt(4)" ::: "memory");   // chunk c+1 landed
    } else if (c == NCH_ - 2) {
      asm volatile("s_waitcnt vmcnt(0)" ::: "memory");   // drain final chunk
    }
    __builtin_amdgcn_s_barrier();          // publish chunk c+1
    asm volatile("" ::: "memory");
  }
#undef GU_ISSUE

  int rq = lane >> 4;
  #pragma unroll
  for (int g = 0; g < 2; ++g) {
    int i = itile * 64 + wn * 32 + g * 16 + fm;
    float bg_ = gb[e * 2 * I_ + 2 * i];
    float bu_ = gb[e * 2 * I_ + 2 * i + 1];
    #pragma unroll
    for (int f = 0; f < 4; ++f) {
      #pragma unroll
      for (int r = 0; r < 4; ++r) {
        int m = wm * 64 + f * 16 + rq * 4 + r;
        int enc = toks[m];
        if (enc < 0) continue;
        float gv = accg[f][g][r] + bg_;
        float uv = accu[f][g][r] + bu_;
        gv = fminf(gv, LIMIT_);
        uv = fminf(fmaxf(uv, -LIMIT_), LIMIT_);
        float glu = gv / (1.f + __expf(-ALPHA_ * gv));
        act[(size_t)enc * I_ + i] = f2bf((uv + 1.f) * glu);
      }
    }
  }
}

// ---------------------------------------------------------------------------
// Kernel 3: down-proj, same pipeline. M=128 tokens x N=128 h, wave-tile
// 64x64 (acc[4][4], 16 MFMA/chunk). Epilogue accumulates directly into
// routed[] via atomicAdd (combine kernel eliminated; routed pre-zeroed).
// ---------------------------------------------------------------------------
__global__ __launch_bounds__(256)
void down_mfma(const unsigned short* __restrict__ act,  // [T*4][I] bf16
               const unsigned short* __restrict__ wdt,  // [E][H][I] bf16
               const float* __restrict__ db,            // [E][H]
               const int* __restrict__ counts,
               const int* __restrict__ tok_list,
               const float* __restrict__ w_list,
               float* __restrict__ routed) {            // [T][H] fp32 (zeroed)
  // 1024 blocks: xcd=lid&7; s=lid>>3 (0..127); e=xcd*4+(s>>5);
  // rem=s&31: htile=rem>>2 (0..7), tb=rem&3.
  int lid = blockIdx.x;
  int xcd = lid & 7, s = lid >> 3;
  int e = (xcd << 2) + (s >> 5);
  int rem = s & 31;
  int htile = rem >> 2;
  int tb = rem & 3;

  int cnt = counts[e];
  int t0 = tb * 128;
  if (t0 >= cnt) return;
  int tid = threadIdx.x;
  int lane = tid & 63;
  int wave = tid >> 6;
  int wm = wave >> 1, wn = wave & 1;

  __shared__ __align__(16) unsigned short Xs[2][128][32];
  __shared__ __align__(16) unsigned short Wd[2][128][32];
  __shared__ int toks[128];
  __shared__ float tws[128];

  if (tid < 128) {
    int slot = t0 + tid;
    bool ok = slot < cnt;
    toks[tid] = ok ? tok_list[e * T_ + slot] : -1;
    tws[tid]  = ok ? w_list[e * T_ + slot] : 0.f;
  }
  __syncthreads();

  int fm = lane & 15;
  int kc = lane >> 4;
  f4 acc[4][4] = {};

  int srow0 = (wave << 5) + (lane >> 2);
  int srow1 = srow0 + 16;
  int sc0 = ((lane & 3) ^ ((srow0 >> 1) & 3)) << 3;
  int sc1 = ((lane & 3) ^ ((srow1 >> 1) & 3)) << 3;
  int enc0 = toks[srow0], enc1 = toks[srow1];
  const unsigned short* srcA0 =
      act + (size_t)((enc0 < 0) ? 0 : enc0) * I_ + sc0;
  const unsigned short* srcA1 =
      act + (size_t)((enc1 < 0) ? 0 : enc1) * I_ + sc1;
  const unsigned short* wbase = wdt + (size_t)e * H_ * I_;
  const unsigned short* srcB0 = wbase + (size_t)(htile * 128 + srow0) * I_ + sc0;
  const unsigned short* srcB1 = wbase + (size_t)(htile * 128 + srow1) * I_ + sc1;

  int ar[4], ac_[4];
  #pragma unroll
  for (int f = 0; f < 4; ++f) {
    int r = wm * 64 + f * 16 + fm;
    ar[f] = r;
    ac_[f] = (kc ^ ((r >> 1) & 3)) << 3;
  }
  int brg[4], bcg[4];
  #pragma unroll
  for (int g = 0; g < 4; ++g) {
    int r = wn * 64 + g * 16 + fm;
    brg[g] = r;
    bcg[g] = (kc ^ ((r >> 1) & 3)) << 3;
  }

#define DN_ISSUE(CC, P)                                                      \
  {                                                                          \
    gload_lds16(srcA0 + (size_t)(CC) * 32, &Xs[P][(wave << 5)][0]);          \
    gload_lds16(srcA1 + (size_t)(CC) * 32, &Xs[P][(wave << 5) + 16][0]);     \
    gload_lds16(srcB0 + (size_t)(CC) * 32, &Wd[P][(wave << 5)][0]);          \
    gload_lds16(srcB1 + (size_t)(CC) * 32, &Wd[P][(wave << 5) + 16][0]);     \
  }

  DN_ISSUE(0, 0)
  DN_ISSUE(1, 1)
  asm volatile("s_waitcnt vmcnt(4)" ::: "memory");
  __builtin_amdgcn_s_barrier();
  asm volatile("" ::: "memory");

  for (int c = 0; c < NCH_; ++c) {
    int P = c & 1;
    {
      s8 a[4];
      #pragma unroll
      for (int f = 0; f < 4; ++f) a[f] = *(const s8*)&Xs[P][ar[f]][ac_[f]];
      #pragma unroll
      for (int g = 0; g < 4; ++g) {
        s8 b = *(const s8*)&Wd[P][brg[g]][bcg[g]];
        #pragma unroll
        for (int f = 0; f < 4; ++f)
          acc[f][g] = __builtin_amdgcn_mfma_f32_16x16x32_bf16(a[f], b, acc[f][g], 0, 0, 0);
      }
    }
    __builtin_amdgcn_s_barrier();
    asm volatile("" ::: "memory");
    if (c < NCH_ - 2) {
      DN_ISSUE(c + 2, P)
      asm volatile("s_waitcnt vmcnt(4)" ::: "memory");
    } else if (c == NCH_ - 2) {
      asm volatile("s_waitcnt vmcnt(0)" ::: "memory");
    }
    __builtin_amdgcn_s_barrier();
    asm volatile("" ::: "memory");
  }
#undef DN_ISSUE

  int rq = lane >> 4;
  #pragma unroll
  for (int g = 0; g < 4; ++g) {
    int h = htile * 128 + wn * 64 + g * 16 + fm;
    float bias = db[e * H_ + h];
    #pragma unroll
    for (int f = 0; f < 4; ++f) {
      #pragma unroll
      for (int r = 0; r < 4; ++r) {
        int m = wm * 64 + f * 16 + rq * 4 + r;
        int enc = toks[m];
        if (enc < 0) continue;
        atomicAdd(&routed[(size_t)(enc >> 2) * H_ + h],
                  (acc[f][g][r] + bias) * tws[m]);
      }
    }
  }
}

// ---------------------------------------------------------------------------
// Workspace: counts@0, tok_list@1MiB, w_list, xbf@2MiB(4MiB), act@8MiB(16MiB),
// wgu@24MiB(128MiB), wdt@152MiB(64MiB). Total 216 MiB. No dsout.
// ---------------------------------------------------------------------------
extern "C" void kernel_launch(void* const* d_in, const int* in_sizes, int n_in,
                              void* d_out, int out_size, void* d_ws, size_t ws_size,
                              hipStream_t stream) {
  (void)in_sizes; (void)n_in; (void)out_size; (void)ws_size;
  const float* x    = (const float*)d_in[0];
  const float* gup  = (const float*)d_in[1];
  const float* gupb = (const float*)d_in[2];
  const float* dwn  = (const float*)d_in[3];
  const float* dwnb = (const float*)d_in[4];
  const float* rw   = (const float*)d_in[5];
  const float* rb   = (const float*)d_in[6];

  float* routed = (float*)d_out;
  float* scores = (float*)d_out + (size_t)T_ * H_;

  char* ws = (char*)d_ws;
  int*   counts   = (int*)ws;
  int*   tok_list = (int*)(ws + ((size_t)1 << 20));
  float* w_list   = (float*)(ws + ((size_t)1 << 20) + (size_t)E_ * T_ * 4);
  unsigned short* xbf = (unsigned short*)(ws + ((size_t)2 << 20));
  unsigned short* act = (unsigned short*)(ws + ((size_t)8 << 20));
  unsigned short* wgu_b = (unsigned short*)(ws + ((size_t)24 << 20));
  unsigned short* wdt_b = (unsigned short*)(ws + ((size_t)24 << 20)
                                            + (size_t)E_ * 2 * I_ * H_ * 2);

  hipMemsetAsync(counts, 0, E_ * sizeof(int), stream);
  hipMemsetAsync(routed, 0, (size_t)T_ * H_ * sizeof(float), stream);

  prep_kernel<<<NB_RTR_ + NB_CAST_ + NB_TGUP_ + NB_TDWN_, 256, 0, stream>>>(
      x, rw, rb, gup, dwn, scores, counts, tok_list, w_list, xbf, wgu_b, wdt_b);
  gateup_mfma<<<2048, 256, 0, stream>>>(xbf, wgu_b, gupb, counts, tok_list, act);
  down_mfma<<<1024, 256, 0, stream>>>(act, wdt_b, dwnb, counts, tok_list,
                                      w_list, routed);
}

// Round 6
// 740.309 us; speedup vs baseline: 1.0151x; 1.0151x over previous
//
#include <hip/hip_runtime.h>
#include <cstdint>
#include <cstddef>

#define E_ 32
#define TOPK_ 4
#define H_ 1024
#define I_ 1024
#define T_ 2048
#define ALPHA_ 1.702f
#define LIMIT_ 7.0f
#define NCH_ 32   // K chunks (K=1024 / BK=32)

// prep grid sections
#define NB_RTR_  2048
#define NB_CAST_ 1024
#define NB_TGUP_ 2048
#define NB_TDWN_ 1024
#define NB_ZERO_ 2048

typedef __attribute__((ext_vector_type(8))) short s8;
typedef __attribute__((ext_vector_type(4))) float f4;

__device__ __forceinline__ unsigned short f2bf(float f) {
  unsigned int u = __float_as_uint(f);
  return (unsigned short)((u + 0x7fffu + ((u >> 16) & 1u)) >> 16);
}

// async global -> LDS, 16 B per lane. LDS dest wave-uniform base; HW writes
// base + lane*16. Global src per-lane (enables source-side swizzle).
__device__ __forceinline__ void gload_lds16(const unsigned short* g,
                                            unsigned short* l) {
  __builtin_amdgcn_global_load_lds(
      (const __attribute__((address_space(1))) void*)g,
      (__attribute__((address_space(3))) void*)l, 16, 0, 0);
}

// ---------------------------------------------------------------------------
// Transpose+cast v2: 256k x 128n tile.
//  read : per instr 2x512 B contiguous row segments (half-wave per row)
//  LDS  : column-major [n=128][k=256 (+8 pad)] bf16, b128 writes/reads
//  write: per instr 2x512 B contiguous column segments
// deint=1 splits even/odd source cols into gate/up planes.
// ---------------------------------------------------------------------------
__device__ __forceinline__ void transpose_body2(
    const float* __restrict__ src, unsigned short* __restrict__ dst,
    int src_rows, int src_cols, int deint, int e, int kbase, int cbase,
    int tid, unsigned short (*ldsT)[264]) {
  int l = tid & 63, w = tid >> 6;
  const float* sp = src + (size_t)e * src_rows * src_cols
                  + (size_t)kbase * src_cols + cbase;
  int halfw = l >> 5;            // 0/1
  int m = l & 31;
  int c4 = m * 4;                // source col of v.x
  int n0, n1, n2, n3;            // LDS cols for v.x..v.w
  if (deint) { n0 = m * 2; n1 = 64 + m * 2; n2 = m * 2 + 1; n3 = 65 + m * 2; }
  else       { n0 = c4; n1 = c4 + 1; n2 = c4 + 2; n3 = c4 + 3; }
  int rgrp = (w * 2 + halfw) * 8;   // 0,8,...,56

  #pragma unroll
  for (int o = 0; o < 4; ++o) {
    int krow = o * 64 + rgrp;
    s8 a0, a1, a2, a3;
    #pragma unroll
    for (int s = 0; s < 8; ++s) {
      float4 v = *(const float4*)(sp + (size_t)(krow + s) * src_cols + c4);
      a0[s] = (short)f2bf(v.x);
      a1[s] = (short)f2bf(v.y);
      a2[s] = (short)f2bf(v.z);
      a3[s] = (short)f2bf(v.w);
    }
    *(s8*)&ldsT[n0][krow] = a0;
    *(s8*)&ldsT[n1][krow] = a1;
    *(s8*)&ldsT[n2][krow] = a2;
    *(s8*)&ldsT[n3][krow] = a3;
  }
  __syncthreads();

  int kc = m * 8;                // k-offset of this lane's 16 B chunk
  int cw = w * 2 + halfw;        // col group 0..7
  #pragma unroll
  for (int s = 0; s < 16; ++s) {
    int n = cw + s * 8;          // local output col 0..127
    s8 v = *(const s8*)&ldsT[n][kc];
    size_t off;
    if (deint) {
      size_t plane = (n >= 64) ? 1 : 0;
      size_t i = (size_t)(cbase >> 1) + (n & 63);
      off = (size_t)e * src_cols * src_rows
          + plane * (size_t)(src_cols >> 1) * src_rows
          + i * src_rows + kbase + kc;
    } else {
      off = (size_t)e * src_cols * src_rows
          + (size_t)(cbase + n) * src_rows + kbase + kc;
    }
    *(s8*)(dst + off) = v;
  }
  __syncthreads();
}

// ---------------------------------------------------------------------------
// Kernel 1: fused prep = router | cast_x | T(gup) | T(dwn) | zero(routed).
// ---------------------------------------------------------------------------
__global__ __launch_bounds__(256)
void prep_kernel(const float* __restrict__ x,
                 const float* __restrict__ rw,
                 const float* __restrict__ rb,
                 const float* __restrict__ gup,
                 const float* __restrict__ dwn,
                 float* __restrict__ scores,
                 int* __restrict__ counts,
                 int* __restrict__ tok_list,
                 float* __restrict__ w_list,
                 unsigned short* __restrict__ xbf,
                 unsigned short* __restrict__ wgu_b,
                 unsigned short* __restrict__ wdt_b,
                 float* __restrict__ routed) {
  __shared__ __align__(16) unsigned short ldsT[128][264];
  int bid = blockIdx.x;
  int tid = threadIdx.x;

  if (bid < NB_RTR_) {
    // ---- router ----
    float* partial = (float*)ldsT;            // 256
    float* logits  = partial + 256;           // 32
    int t = bid;
    int e = tid & 31, q = tid >> 5;
    const float4* xp = (const float4*)(x + (size_t)t * H_ + q * 128);
    const float4* wp = (const float4*)(rw + (size_t)e * H_ + q * 128);
    float s = 0.f;
    #pragma unroll 8
    for (int h = 0; h < 32; ++h) {
      float4 a = xp[h], b = wp[h];
      s += a.x * b.x + a.y * b.y + a.z * b.z + a.w * b.w;
    }
    partial[tid] = s;
    __syncthreads();
    if (tid < 32) {
      float acc = 0.f;
      #pragma unroll
      for (int j = 0; j < 8; ++j) acc += partial[j * 32 + tid];
      logits[tid] = acc + rb[tid];
    }
    __syncthreads();
    if (tid == 0) {
      float l[E_];
      #pragma unroll
      for (int i = 0; i < E_; ++i) l[i] = logits[i];
      int idx[TOPK_]; float v[TOPK_];
      for (int k = 0; k < TOPK_; ++k) {
        int bi = 0; float bv = -1e30f;
        #pragma unroll
        for (int i = 0; i < E_; ++i)
          if (l[i] > bv) { bv = l[i]; bi = i; }
        idx[k] = bi; v[k] = bv; l[bi] = -1e30f;
      }
      float m = v[0], den = 0.f, w[TOPK_];
      #pragma unroll
      for (int k = 0; k < TOPK_; ++k) { w[k] = expf(v[k] - m); den += w[k]; }
      float inv = 1.f / den;
      float* srow = scores + (size_t)t * E_;
      #pragma unroll
      for (int i = 0; i < E_; ++i) srow[i] = 0.f;
      for (int k = 0; k < TOPK_; ++k) {
        float wk = w[k] * inv;
        srow[idx[k]] = wk;
        int pos = atomicAdd(&counts[idx[k]], 1);
        tok_list[idx[k] * T_ + pos] = t * TOPK_ + k;
        w_list[idx[k] * T_ + pos] = wk;
      }
    }
  } else if (bid < NB_RTR_ + NB_CAST_) {
    // ---- x fp32 -> bf16 ----
    int b2 = bid - NB_RTR_;
    size_t i = (size_t)(b2 * 256 + tid) * 8;
    float4 a = *(const float4*)(x + i);
    float4 b = *(const float4*)(x + i + 4);
    s8 v;
    v[0] = (short)f2bf(a.x); v[1] = (short)f2bf(a.y);
    v[2] = (short)f2bf(a.z); v[3] = (short)f2bf(a.w);
    v[4] = (short)f2bf(b.x); v[5] = (short)f2bf(b.y);
    v[6] = (short)f2bf(b.z); v[7] = (short)f2bf(b.w);
    *(s8*)(xbf + i) = v;
  } else if (bid < NB_RTR_ + NB_CAST_ + NB_TGUP_) {
    // ---- gate_up: [E][H][2I] -> [E][2][I][H] bf16 ----
    int b3 = bid - (NB_RTR_ + NB_CAST_);
    int e = b3 >> 6;
    int rem = b3 & 63;
    int kbase = (rem >> 4) * 256;    // 4 k-tiles over H
    int cbase = (rem & 15) * 128;    // 16 c-tiles over 2I
    transpose_body2(gup, wgu_b, H_, 2 * I_, 1, e, kbase, cbase, tid, ldsT);
  } else if (bid < NB_RTR_ + NB_CAST_ + NB_TGUP_ + NB_TDWN_) {
    // ---- down: [E][I][H] -> [E][H][I] bf16 ----
    int b4 = bid - (NB_RTR_ + NB_CAST_ + NB_TGUP_);
    int e = b4 >> 5;
    int rem = b4 & 31;
    int kbase = (rem >> 3) * 256;    // 4 k-tiles over I
    int cbase = (rem & 7) * 128;     // 8 c-tiles over H
    transpose_body2(dwn, wdt_b, I_, H_, 0, e, kbase, cbase, tid, ldsT);
  } else {
    // ---- zero routed (replaces hipMemsetAsync dispatch) ----
    int b5 = bid - (NB_RTR_ + NB_CAST_ + NB_TGUP_ + NB_TDWN_);
    float4 z = {0.f, 0.f, 0.f, 0.f};
    *(float4*)(routed + (size_t)b5 * 1024 + tid * 4) = z;
  }
}

// ---------------------------------------------------------------------------
// Kernel 2: gate_up, bf16 MFMA, async gload_lds pipeline (unchanged from r5).
// ---------------------------------------------------------------------------
__global__ __launch_bounds__(256)
void gateup_mfma(const unsigned short* __restrict__ xb,   // [T][H] bf16
                 const unsigned short* __restrict__ wgu,  // [E][2][I][H] bf16
                 const float* __restrict__ gb,            // [E][2I]
                 const int* __restrict__ counts,
                 const int* __restrict__ tok_list,
                 unsigned short* __restrict__ act) {      // [T*4][I] bf16
  int lid = blockIdx.x;
  int xcd = lid & 7, s = lid >> 3;
  int e = (xcd << 2) + (s >> 6);
  int rem = s & 63;
  int itile = rem >> 2;
  int tb = rem & 3;

  int cnt = counts[e];
  int t0 = tb * 128;
  if (t0 >= cnt) return;
  int tid = threadIdx.x;
  int lane = tid & 63;
  int wave = tid >> 6;
  int wm = wave >> 1, wn = wave & 1;

  __shared__ __align__(16) unsigned short Xs[2][128][32];
  __shared__ __align__(16) unsigned short Wg[2][128][32];
  __shared__ int toks[128];

  if (tid < 128) {
    int slot = t0 + tid;
    toks[tid] = (slot < cnt) ? tok_list[e * T_ + slot] : -1;
  }
  __syncthreads();

  int fm = lane & 15;
  int kc = lane >> 4;
  f4 accg[4][2] = {};
  f4 accu[4][2] = {};

  int srow0 = (wave << 5) + (lane >> 2);
  int srow1 = srow0 + 16;
  int sc0 = ((lane & 3) ^ ((srow0 >> 1) & 3)) << 3;
  int sc1 = ((lane & 3) ^ ((srow1 >> 1) & 3)) << 3;
  int enc0 = toks[srow0], enc1 = toks[srow1];
  const unsigned short* srcA0 =
      xb + (size_t)((enc0 < 0) ? 0 : (enc0 >> 2)) * H_ + sc0;
  const unsigned short* srcA1 =
      xb + (size_t)((enc1 < 0) ? 0 : (enc1 >> 2)) * H_ + sc1;
  size_t R0 = (srow0 < 64) ? (size_t)(itile * 64 + srow0)
                           : (size_t)(I_ + itile * 64 + (srow0 - 64));
  size_t R1 = (srow1 < 64) ? (size_t)(itile * 64 + srow1)
                           : (size_t)(I_ + itile * 64 + (srow1 - 64));
  const unsigned short* wbase = wgu + (size_t)e * 2 * I_ * H_;
  const unsigned short* srcB0 = wbase + R0 * H_ + sc0;
  const unsigned short* srcB1 = wbase + R1 * H_ + sc1;

  int ar[4], ac[4];
  #pragma unroll
  for (int f = 0; f < 4; ++f) {
    int r = wm * 64 + f * 16 + fm;
    ar[f] = r;
    ac[f] = (kc ^ ((r >> 1) & 3)) << 3;
  }
  int brg[2], bcg[2];
  #pragma unroll
  for (int g = 0; g < 2; ++g) {
    int r = wn * 32 + g * 16 + fm;
    brg[g] = r;
    bcg[g] = (kc ^ ((r >> 1) & 3)) << 3;
  }

#define GU_ISSUE(CC, P)                                                      \
  {                                                                          \
    gload_lds16(srcA0 + (size_t)(CC) * 32, &Xs[P][(wave << 5)][0]);          \
    gload_lds16(srcA1 + (size_t)(CC) * 32, &Xs[P][(wave << 5) + 16][0]);     \
    gload_lds16(srcB0 + (size_t)(CC) * 32, &Wg[P][(wave << 5)][0]);          \
    gload_lds16(srcB1 + (size_t)(CC) * 32, &Wg[P][(wave << 5) + 16][0]);     \
  }

  GU_ISSUE(0, 0)
  GU_ISSUE(1, 1)
  asm volatile("s_waitcnt vmcnt(4)" ::: "memory");
  __builtin_amdgcn_s_barrier();
  asm volatile("" ::: "memory");

  for (int c = 0; c < NCH_; ++c) {
    int P = c & 1;
    {
      s8 a[4];
      #pragma unroll
      for (int f = 0; f < 4; ++f) a[f] = *(const s8*)&Xs[P][ar[f]][ac[f]];
      #pragma unroll
      for (int g = 0; g < 2; ++g) {
        s8 bg = *(const s8*)&Wg[P][brg[g]][bcg[g]];
        s8 bu = *(const s8*)&Wg[P][64 + brg[g]][bcg[g]];
        #pragma unroll
        for (int f = 0; f < 4; ++f) {
          accg[f][g] = __builtin_amdgcn_mfma_f32_16x16x32_bf16(a[f], bg, accg[f][g], 0, 0, 0);
          accu[f][g] = __builtin_amdgcn_mfma_f32_16x16x32_bf16(a[f], bu, accu[f][g], 0, 0, 0);
        }
      }
    }
    __builtin_amdgcn_s_barrier();
    asm volatile("" ::: "memory");
    if (c < NCH_ - 2) {
      GU_ISSUE(c + 2, P)
      asm volatile("s_waitcnt vmcnt(4)" ::: "memory");
    } else if (c == NCH_ - 2) {
      asm volatile("s_waitcnt vmcnt(0)" ::: "memory");
    }
    __builtin_amdgcn_s_barrier();
    asm volatile("" ::: "memory");
  }
#undef GU_ISSUE

  int rq = lane >> 4;
  #pragma unroll
  for (int g = 0; g < 2; ++g) {
    int i = itile * 64 + wn * 32 + g * 16 + fm;
    float bg_ = gb[e * 2 * I_ + 2 * i];
    float bu_ = gb[e * 2 * I_ + 2 * i + 1];
    #pragma unroll
    for (int f = 0; f < 4; ++f) {
      #pragma unroll
      for (int r = 0; r < 4; ++r) {
        int m = wm * 64 + f * 16 + rq * 4 + r;
        int enc = toks[m];
        if (enc < 0) continue;
        float gv = accg[f][g][r] + bg_;
        float uv = accu[f][g][r] + bu_;
        gv = fminf(gv, LIMIT_);
        uv = fminf(fmaxf(uv, -LIMIT_), LIMIT_);
        float glu = gv / (1.f + __expf(-ALPHA_ * gv));
        act[(size_t)enc * I_ + i] = f2bf((uv + 1.f) * glu);
      }
    }
  }
}

// ---------------------------------------------------------------------------
// Kernel 3: down-proj (unchanged from r5). atomicAdd into pre-zeroed routed.
// ---------------------------------------------------------------------------
__global__ __launch_bounds__(256)
void down_mfma(const unsigned short* __restrict__ act,  // [T*4][I] bf16
               const unsigned short* __restrict__ wdt,  // [E][H][I] bf16
               const float* __restrict__ db,            // [E][H]
               const int* __restrict__ counts,
               const int* __restrict__ tok_list,
               const float* __restrict__ w_list,
               float* __restrict__ routed) {            // [T][H] fp32 (zeroed)
  int lid = blockIdx.x;
  int xcd = lid & 7, s = lid >> 3;
  int e = (xcd << 2) + (s >> 5);
  int rem = s & 31;
  int htile = rem >> 2;
  int tb = rem & 3;

  int cnt = counts[e];
  int t0 = tb * 128;
  if (t0 >= cnt) return;
  int tid = threadIdx.x;
  int lane = tid & 63;
  int wave = tid >> 6;
  int wm = wave >> 1, wn = wave & 1;

  __shared__ __align__(16) unsigned short Xs[2][128][32];
  __shared__ __align__(16) unsigned short Wd[2][128][32];
  __shared__ int toks[128];
  __shared__ float tws[128];

  if (tid < 128) {
    int slot = t0 + tid;
    bool ok = slot < cnt;
    toks[tid] = ok ? tok_list[e * T_ + slot] : -1;
    tws[tid]  = ok ? w_list[e * T_ + slot] : 0.f;
  }
  __syncthreads();

  int fm = lane & 15;
  int kc = lane >> 4;
  f4 acc[4][4] = {};

  int srow0 = (wave << 5) + (lane >> 2);
  int srow1 = srow0 + 16;
  int sc0 = ((lane & 3) ^ ((srow0 >> 1) & 3)) << 3;
  int sc1 = ((lane & 3) ^ ((srow1 >> 1) & 3)) << 3;
  int enc0 = toks[srow0], enc1 = toks[srow1];
  const unsigned short* srcA0 =
      act + (size_t)((enc0 < 0) ? 0 : enc0) * I_ + sc0;
  const unsigned short* srcA1 =
      act + (size_t)((enc1 < 0) ? 0 : enc1) * I_ + sc1;
  const unsigned short* wbase = wdt + (size_t)e * H_ * I_;
  const unsigned short* srcB0 = wbase + (size_t)(htile * 128 + srow0) * I_ + sc0;
  const unsigned short* srcB1 = wbase + (size_t)(htile * 128 + srow1) * I_ + sc1;

  int ar[4], ac_[4];
  #pragma unroll
  for (int f = 0; f < 4; ++f) {
    int r = wm * 64 + f * 16 + fm;
    ar[f] = r;
    ac_[f] = (kc ^ ((r >> 1) & 3)) << 3;
  }
  int brg[4], bcg[4];
  #pragma unroll
  for (int g = 0; g < 4; ++g) {
    int r = wn * 64 + g * 16 + fm;
    brg[g] = r;
    bcg[g] = (kc ^ ((r >> 1) & 3)) << 3;
  }

#define DN_ISSUE(CC, P)                                                      \
  {                                                                          \
    gload_lds16(srcA0 + (size_t)(CC) * 32, &Xs[P][(wave << 5)][0]);          \
    gload_lds16(srcA1 + (size_t)(CC) * 32, &Xs[P][(wave << 5) + 16][0]);     \
    gload_lds16(srcB0 + (size_t)(CC) * 32, &Wd[P][(wave << 5)][0]);          \
    gload_lds16(srcB1 + (size_t)(CC) * 32, &Wd[P][(wave << 5) + 16][0]);     \
  }

  DN_ISSUE(0, 0)
  DN_ISSUE(1, 1)
  asm volatile("s_waitcnt vmcnt(4)" ::: "memory");
  __builtin_amdgcn_s_barrier();
  asm volatile("" ::: "memory");

  for (int c = 0; c < NCH_; ++c) {
    int P = c & 1;
    {
      s8 a[4];
      #pragma unroll
      for (int f = 0; f < 4; ++f) a[f] = *(const s8*)&Xs[P][ar[f]][ac_[f]];
      #pragma unroll
      for (int g = 0; g < 4; ++g) {
        s8 b = *(const s8*)&Wd[P][brg[g]][bcg[g]];
        #pragma unroll
        for (int f = 0; f < 4; ++f)
          acc[f][g] = __builtin_amdgcn_mfma_f32_16x16x32_bf16(a[f], b, acc[f][g], 0, 0, 0);
      }
    }
    __builtin_amdgcn_s_barrier();
    asm volatile("" ::: "memory");
    if (c < NCH_ - 2) {
      DN_ISSUE(c + 2, P)
      asm volatile("s_waitcnt vmcnt(4)" ::: "memory");
    } else if (c == NCH_ - 2) {
      asm volatile("s_waitcnt vmcnt(0)" ::: "memory");
    }
    __builtin_amdgcn_s_barrier();
    asm volatile("" ::: "memory");
  }
#undef DN_ISSUE

  int rq = lane >> 4;
  #pragma unroll
  for (int g = 0; g < 4; ++g) {
    int h = htile * 128 + wn * 64 + g * 16 + fm;
    float bias = db[e * H_ + h];
    #pragma unroll
    for (int f = 0; f < 4; ++f) {
      #pragma unroll
      for (int r = 0; r < 4; ++r) {
        int m = wm * 64 + f * 16 + rq * 4 + r;
        int enc = toks[m];
        if (enc < 0) continue;
        atomicAdd(&routed[(size_t)(enc >> 2) * H_ + h],
                  (acc[f][g][r] + bias) * tws[m]);
      }
    }
  }
}

// ---------------------------------------------------------------------------
// Workspace: counts@0, tok_list@1MiB, w_list, xbf@2MiB(4MiB), act@8MiB(16MiB),
// wgu@24MiB(128MiB), wdt@152MiB(64MiB). Total 216 MiB.
// ---------------------------------------------------------------------------
extern "C" void kernel_launch(void* const* d_in, const int* in_sizes, int n_in,
                              void* d_out, int out_size, void* d_ws, size_t ws_size,
                              hipStream_t stream) {
  (void)in_sizes; (void)n_in; (void)out_size; (void)ws_size;
  const float* x    = (const float*)d_in[0];
  const float* gup  = (const float*)d_in[1];
  const float* gupb = (const float*)d_in[2];
  const float* dwn  = (const float*)d_in[3];
  const float* dwnb = (const float*)d_in[4];
  const float* rw   = (const float*)d_in[5];
  const float* rb   = (const float*)d_in[6];

  float* routed = (float*)d_out;
  float* scores = (float*)d_out + (size_t)T_ * H_;

  char* ws = (char*)d_ws;
  int*   counts   = (int*)ws;
  int*   tok_list = (int*)(ws + ((size_t)1 << 20));
  float* w_list   = (float*)(ws + ((size_t)1 << 20) + (size_t)E_ * T_ * 4);
  unsigned short* xbf = (unsigned short*)(ws + ((size_t)2 << 20));
  unsigned short* act = (unsigned short*)(ws + ((size_t)8 << 20));
  unsigned short* wgu_b = (unsigned short*)(ws + ((size_t)24 << 20));
  unsigned short* wdt_b = (unsigned short*)(ws + ((size_t)24 << 20)
                                            + (size_t)E_ * 2 * I_ * H_ * 2);

  hipMemsetAsync(counts, 0, E_ * sizeof(int), stream);

  prep_kernel<<<NB_RTR_ + NB_CAST_ + NB_TGUP_ + NB_TDWN_ + NB_ZERO_, 256, 0,
                stream>>>(x, rw, rb, gup, dwn, scores, counts, tok_list,
                          w_list, xbf, wgu_b, wdt_b, routed);
  gateup_mfma<<<2048, 256, 0, stream>>>(xbf, wgu_b, gupb, counts, tok_list, act);
  down_mfma<<<1024, 256, 0, stream>>>(act, wdt_b, dwnb, counts, tok_list,
                                      w_list, routed);
}